// Round 5
// baseline (23.713 us; speedup 1.0000x reference)
//
#include <hip/hip_runtime.h>

// Problem constants: B=16, C=5, H=512, W=512
constexpr int Bn      = 16;
constexpr int Cn      = 5;
constexpr int HW      = 512 * 512;        // 262144
constexpr int HW4     = HW / 4;           // 65536 float4 groups per (b,c) plane
constexpr int NVEC    = Bn * HW / 4;      // 1,048,576 4-pixel groups
constexpr int NBLK    = 1024;             // one full residency round (4 blk/CU x 256 CU)
constexpr int THREADS = 256;
constexpr int STRIDE  = NBLK * THREADS;   // 262144 == NVEC/4; +STRIDE => batch+4, same hw4
constexpr float SCALE = 1.0f / (float)(Bn * HW);

__device__ __forceinline__ float block_reduce_256(float v) {
    #pragma unroll
    for (int off = 32; off > 0; off >>= 1)
        v += __shfl_down(v, off, 64);
    __shared__ float s[4];
    const int lane = threadIdx.x & 63;
    const int wid  = threadIdx.x >> 6;
    if (lane == 0) s[wid] = v;
    __syncthreads();
    if (threadIdx.x == 0) v = (s[0] + s[1]) + (s[2] + s[3]);
    return v;
}

__device__ __forceinline__ float pixel_pen(float l0, float l1, float l2, float l3,
                                           float l4, int t) {
    // relu terms on unnormalized exps; single divide by partition sum (S>0).
    float m  = fmaxf(fmaxf(fmaxf(l0, l1), fmaxf(l2, l3)), l4);
    float e0 = __expf(l0 - m);
    float e1 = __expf(l1 - m);
    float e2 = __expf(l2 - m);
    float e3 = __expf(l3 - m);
    float e4 = __expf(l4 - m);
    float S  = ((e0 + e1) + (e2 + e3)) + e4;
    float d1 = e1 - e0;
    float d2 = e2 - e1;
    float d3 = e3 - e2;
    float d4 = e4 - e3;
    float pen = 0.0f;
    pen += (t >= 1) ? fmaxf(-d1, 0.0f) : fmaxf(d1, 0.0f);
    pen += (t >= 2) ? fmaxf(-d2, 0.0f) : fmaxf(d2, 0.0f);
    pen += (t >= 3) ? fmaxf(-d3, 0.0f) : fmaxf(d3, 0.0f);
    pen += (t >= 4) ? fmaxf(-d4, 0.0f) : fmaxf(d4, 0.0f);
    return pen / S;
}

struct Grp { float4 x0, x1, x2, x3, x4; int4 t; };

__device__ __forceinline__ Grp load_grp(const float4* __restrict__ p,
                                        const int4* __restrict__ lab, int v) {
    Grp g;
    g.t  = lab[v];
    g.x0 = p[0 * HW4];
    g.x1 = p[1 * HW4];
    g.x2 = p[2 * HW4];
    g.x3 = p[3 * HW4];
    g.x4 = p[4 * HW4];
    return g;
}

__device__ __forceinline__ float group_pen(const Grp& g) {
    float a = 0.0f;
    a += pixel_pen(g.x0.x, g.x1.x, g.x2.x, g.x3.x, g.x4.x, g.t.x);
    a += pixel_pen(g.x0.y, g.x1.y, g.x2.y, g.x3.y, g.x4.y, g.t.y);
    a += pixel_pen(g.x0.z, g.x1.z, g.x2.z, g.x3.z, g.x4.z, g.t.z);
    a += pixel_pen(g.x0.w, g.x1.w, g.x2.w, g.x3.w, g.x4.w, g.t.w);
    return a;
}

// 4 waves/SIMD -> <=128 VGPRs; double-buffered: load g[k+1] while computing g[k].
__global__ void __launch_bounds__(256, 4)
o2_loss_partial(const float4* __restrict__ pred,   // (B, 5, H, W) as float4
                const int4*  __restrict__ lab,     // (B, H, W) as int4
                float* __restrict__ partial) {
    const int tid = threadIdx.x;
    const int v0  = blockIdx.x * THREADS + tid;    // in [0, STRIDE)
    const int b0  = v0 >> 16;                      // in [0, 4)
    const int h0  = v0 & (HW4 - 1);
    const float4* p = pred + (size_t)b0 * (Cn * HW4) + h0;
    constexpr int PB = 4 * (Cn * HW4);             // batch+4 step in float4s

    Grp ga = load_grp(p, lab, v0);                                 // g0
    Grp gb = load_grp(p + PB, lab, v0 + STRIDE);                   // g1
    float acc = group_pen(ga);                                     // compute g0
    ga = load_grp(p + 2 * PB, lab, v0 + 2 * STRIDE);               // g2
    acc += group_pen(gb);                                          // compute g1
    gb = load_grp(p + 3 * PB, lab, v0 + 3 * STRIDE);               // g3
    acc += group_pen(ga);                                          // compute g2
    acc += group_pen(gb);                                          // compute g3

    float bsum = block_reduce_256(acc);
    if (tid == 0) partial[blockIdx.x] = bsum;      // plain store, no atomics
}

__global__ void __launch_bounds__(256)
o2_loss_finalize(const float4* __restrict__ partial4, float* __restrict__ out) {
    // 1024 floats = 256 float4: exactly one per thread, fixed order.
    float4 x = partial4[threadIdx.x];
    float v = (x.x + x.y) + (x.z + x.w);
    v = block_reduce_256(v);
    if (threadIdx.x == 0) out[0] = v * SCALE;
}

extern "C" void kernel_launch(void* const* d_in, const int* in_sizes, int n_in,
                              void* d_out, int out_size, void* d_ws, size_t ws_size,
                              hipStream_t stream) {
    const float4* pred = (const float4*)d_in[0];
    const int4*   lab  = (const int4*)d_in[1];
    float* partial = (float*)d_ws;          // 1024 floats = 4 KB scratch
    float* out     = (float*)d_out;

    o2_loss_partial<<<NBLK, THREADS, 0, stream>>>(pred, lab, partial);
    o2_loss_finalize<<<1, THREADS, 0, stream>>>((const float4*)partial, out);
}

// Round 9
// 23.690 us; speedup vs baseline: 1.0010x; 1.0010x over previous
//
#include <hip/hip_runtime.h>

// Problem constants: B=16, C=5, H=512, W=512
constexpr int Bn      = 16;
constexpr int Cn      = 5;
constexpr int HW      = 512 * 512;        // 262144
constexpr int HW4     = HW / 4;           // 65536 float4 groups per (b,c) plane
constexpr int NVEC    = Bn * HW / 4;      // 1,048,576 4-pixel groups
constexpr int NBLK    = 2048;
constexpr int THREADS = 256;
constexpr int STRIDE  = NBLK * THREADS;   // 524288 == NVEC/2; +STRIDE => batch+8, same hw4
constexpr float SCALE = 1.0f / (float)(Bn * HW);

__device__ __forceinline__ float block_reduce_256(float v) {
    #pragma unroll
    for (int off = 32; off > 0; off >>= 1)
        v += __shfl_down(v, off, 64);
    __shared__ float s[4];
    const int lane = threadIdx.x & 63;
    const int wid  = threadIdx.x >> 6;
    if (lane == 0) s[wid] = v;
    __syncthreads();
    if (threadIdx.x == 0) v = (s[0] + s[1]) + (s[2] + s[3]);
    return v;
}

__device__ __forceinline__ float pixel_pen(float l0, float l1, float l2, float l3,
                                           float l4, int t) {
    // relu terms on unnormalized exps; single divide by partition sum (S>0).
    float m  = fmaxf(fmaxf(fmaxf(l0, l1), fmaxf(l2, l3)), l4);
    float e0 = __expf(l0 - m);
    float e1 = __expf(l1 - m);
    float e2 = __expf(l2 - m);
    float e3 = __expf(l3 - m);
    float e4 = __expf(l4 - m);
    float S  = ((e0 + e1) + (e2 + e3)) + e4;
    float d1 = e1 - e0;
    float d2 = e2 - e1;
    float d3 = e3 - e2;
    float d4 = e4 - e3;
    float pen = 0.0f;
    pen += (t >= 1) ? fmaxf(-d1, 0.0f) : fmaxf(d1, 0.0f);
    pen += (t >= 2) ? fmaxf(-d2, 0.0f) : fmaxf(d2, 0.0f);
    pen += (t >= 3) ? fmaxf(-d3, 0.0f) : fmaxf(d3, 0.0f);
    pen += (t >= 4) ? fmaxf(-d4, 0.0f) : fmaxf(d4, 0.0f);
    return pen / S;
}

__device__ __forceinline__ float group_pen(float4 x0, float4 x1, float4 x2,
                                           float4 x3, float4 x4, int4 t) {
    float a = 0.0f;
    a += pixel_pen(x0.x, x1.x, x2.x, x3.x, x4.x, t.x);
    a += pixel_pen(x0.y, x1.y, x2.y, x3.y, x4.y, t.y);
    a += pixel_pen(x0.z, x1.z, x2.z, x3.z, x4.z, t.z);
    a += pixel_pen(x0.w, x1.w, x2.w, x3.w, x4.w, t.w);
    return a;
}

// min 4 waves/SIMD -> <=128 VGPRs: all 14 loads stay in flight.
__global__ void __launch_bounds__(256, 4)
o2_loss_partial(const float4* __restrict__ pred,   // (B, 5, H, W) as float4
                const int4*  __restrict__ lab,     // (B, H, W) as int4
                float* __restrict__ partial) {
    const int tid = threadIdx.x;
    const int v0  = blockIdx.x * THREADS + tid;   // in [0, STRIDE)
    const int b0  = v0 >> 16;
    const int h0  = v0 & (HW4 - 1);
    const float4* p0 = pred + (size_t)b0 * (Cn * HW4) + h0;
    const float4* p1 = p0 + 8 * (Cn * HW4);       // batch+8, same hw4

    // Issue ALL loads up front; with 128-VGPR budget they stay in flight.
    float4 a0 = p0[0 * HW4], a1 = p0[1 * HW4], a2 = p0[2 * HW4],
           a3 = p0[3 * HW4], a4 = p0[4 * HW4];
    float4 c0 = p1[0 * HW4], c1 = p1[1 * HW4], c2 = p1[2 * HW4],
           c3 = p1[3 * HW4], c4 = p1[4 * HW4];
    int4 t0 = lab[v0];
    int4 t1 = lab[v0 + STRIDE];

    float acc = group_pen(a0, a1, a2, a3, a4, t0)
              + group_pen(c0, c1, c2, c3, c4, t1);

    float bsum = block_reduce_256(acc);
    if (tid == 0) partial[blockIdx.x] = bsum;     // plain store, no atomics
}

__global__ void __launch_bounds__(256)
o2_loss_finalize(const float4* __restrict__ partial4, float* __restrict__ out) {
    // 2048 floats = 512 float4; each thread sums 2 in fixed order.
    float4 x = partial4[threadIdx.x];
    float4 y = partial4[threadIdx.x + 256];
    float v = ((x.x + x.y) + (x.z + x.w)) + ((y.x + y.y) + (y.z + y.w));
    v = block_reduce_256(v);
    if (threadIdx.x == 0) out[0] = v * SCALE;
}

extern "C" void kernel_launch(void* const* d_in, const int* in_sizes, int n_in,
                              void* d_out, int out_size, void* d_ws, size_t ws_size,
                              hipStream_t stream) {
    const float4* pred = (const float4*)d_in[0];
    const int4*   lab  = (const int4*)d_in[1];
    float* partial = (float*)d_ws;          // 2048 floats = 8 KB scratch
    float* out     = (float*)d_out;

    o2_loss_partial<<<NBLK, THREADS, 0, stream>>>(pred, lab, partial);
    o2_loss_finalize<<<1, THREADS, 0, stream>>>((const float4*)partial, out);
}

// Round 10
// 23.284 us; speedup vs baseline: 1.0184x; 1.0174x over previous
//
#include <hip/hip_runtime.h>

// Problem constants: B=16, C=5, H=512, W=512
constexpr int Bn      = 16;
constexpr int Cn      = 5;
constexpr int HW      = 512 * 512;        // 262144
constexpr int HW4     = HW / 4;           // 65536 float4 groups per (b,c) plane
constexpr int NVEC    = Bn * HW / 4;      // 1,048,576 4-pixel groups
constexpr int NBLK    = 1024;             // one residency round (4 blk/CU x 256 CU)
constexpr int THREADS = 256;
constexpr int STRIDE  = NBLK * THREADS;   // 262144 == NVEC/4; +STRIDE => batch+4, same hw4
constexpr float SCALE = 1.0f / (float)(Bn * HW);

__device__ __forceinline__ float block_reduce_256(float v) {
    #pragma unroll
    for (int off = 32; off > 0; off >>= 1)
        v += __shfl_down(v, off, 64);
    __shared__ float s[4];
    const int lane = threadIdx.x & 63;
    const int wid  = threadIdx.x >> 6;
    if (lane == 0) s[wid] = v;
    __syncthreads();
    if (threadIdx.x == 0) v = (s[0] + s[1]) + (s[2] + s[3]);
    return v;
}

__device__ __forceinline__ float pixel_pen(float l0, float l1, float l2, float l3,
                                           float l4, int t) {
    // relu terms on unnormalized exps; single divide by partition sum (S>0).
    float m  = fmaxf(fmaxf(fmaxf(l0, l1), fmaxf(l2, l3)), l4);
    float e0 = __expf(l0 - m);
    float e1 = __expf(l1 - m);
    float e2 = __expf(l2 - m);
    float e3 = __expf(l3 - m);
    float e4 = __expf(l4 - m);
    float S  = ((e0 + e1) + (e2 + e3)) + e4;
    float d1 = e1 - e0;
    float d2 = e2 - e1;
    float d3 = e3 - e2;
    float d4 = e4 - e3;
    float pen = 0.0f;
    pen += (t >= 1) ? fmaxf(-d1, 0.0f) : fmaxf(d1, 0.0f);
    pen += (t >= 2) ? fmaxf(-d2, 0.0f) : fmaxf(d2, 0.0f);
    pen += (t >= 3) ? fmaxf(-d3, 0.0f) : fmaxf(d3, 0.0f);
    pen += (t >= 4) ? fmaxf(-d4, 0.0f) : fmaxf(d4, 0.0f);
    return pen / S;
}

struct Grp { float4 x0, x1, x2, x3, x4; int4 t; };

__device__ __forceinline__ Grp load_grp(const float4* __restrict__ p,
                                        const int4* __restrict__ lab, int v) {
    Grp g;
    g.t  = lab[v];
    g.x0 = p[0 * HW4];
    g.x1 = p[1 * HW4];
    g.x2 = p[2 * HW4];
    g.x3 = p[3 * HW4];
    g.x4 = p[4 * HW4];
    return g;
}

__device__ __forceinline__ float group_pen(const Grp& g) {
    float a = 0.0f;
    a += pixel_pen(g.x0.x, g.x1.x, g.x2.x, g.x3.x, g.x4.x, g.t.x);
    a += pixel_pen(g.x0.y, g.x1.y, g.x2.y, g.x3.y, g.x4.y, g.t.y);
    a += pixel_pen(g.x0.z, g.x1.z, g.x2.z, g.x3.z, g.x4.z, g.t.z);
    a += pixel_pen(g.x0.w, g.x1.w, g.x2.w, g.x3.w, g.x4.w, g.t.w);
    return a;
}

// 4 waves/SIMD -> <=128 VGPRs; double-buffered: load g[k+1] while computing g[k].
// (r5 form: measured equal to the 2048-block r4 form, but leaves only 1024
//  partials -> cheaper finalize.)
__global__ void __launch_bounds__(256, 4)
o2_loss_partial(const float4* __restrict__ pred,   // (B, 5, H, W) as float4
                const int4*  __restrict__ lab,     // (B, H, W) as int4
                float* __restrict__ partial) {
    const int tid = threadIdx.x;
    const int v0  = blockIdx.x * THREADS + tid;    // in [0, STRIDE)
    const int b0  = v0 >> 16;                      // in [0, 4)
    const int h0  = v0 & (HW4 - 1);
    const float4* p = pred + (size_t)b0 * (Cn * HW4) + h0;
    constexpr int PB = 4 * (Cn * HW4);             // batch+4 step in float4s

    Grp ga = load_grp(p, lab, v0);                                 // g0
    Grp gb = load_grp(p + PB, lab, v0 + STRIDE);                   // g1
    float acc = group_pen(ga);                                     // compute g0
    ga = load_grp(p + 2 * PB, lab, v0 + 2 * STRIDE);               // g2
    acc += group_pen(gb);                                          // compute g1
    gb = load_grp(p + 3 * PB, lab, v0 + 3 * STRIDE);               // g3
    acc += group_pen(ga);                                          // compute g2
    acc += group_pen(gb);                                          // compute g3

    float bsum = block_reduce_256(acc);
    if (tid == 0) partial[blockIdx.x] = bsum;      // plain store, no atomics
}

// Single-wave finalize: no LDS, no __syncthreads, 4 independent float4 loads
// per lane (one memory round trip), shuffle reduce, one store.
__global__ void __launch_bounds__(64)
o2_loss_finalize(const float4* __restrict__ partial4, float* __restrict__ out) {
    const int lane = threadIdx.x;                  // 0..63
    float4 x0 = partial4[lane];
    float4 x1 = partial4[lane + 64];
    float4 x2 = partial4[lane + 128];
    float4 x3 = partial4[lane + 192];
    float v = (((x0.x + x0.y) + (x0.z + x0.w)) + ((x1.x + x1.y) + (x1.z + x1.w)))
            + (((x2.x + x2.y) + (x2.z + x2.w)) + ((x3.x + x3.y) + (x3.z + x3.w)));
    #pragma unroll
    for (int off = 32; off > 0; off >>= 1)
        v += __shfl_down(v, off, 64);
    if (lane == 0) out[0] = v * SCALE;
}

extern "C" void kernel_launch(void* const* d_in, const int* in_sizes, int n_in,
                              void* d_out, int out_size, void* d_ws, size_t ws_size,
                              hipStream_t stream) {
    const float4* pred = (const float4*)d_in[0];
    const int4*   lab  = (const int4*)d_in[1];
    float* partial = (float*)d_ws;          // 1024 floats = 4 KB scratch
    float* out     = (float*)d_out;

    o2_loss_partial<<<NBLK, THREADS, 0, stream>>>(pred, lab, partial);
    o2_loss_finalize<<<1, 64, 0, stream>>>((const float4*)partial, out);
}

// Round 12
// 23.271 us; speedup vs baseline: 1.0190x; 1.0005x over previous
//
#include <hip/hip_runtime.h>

// Problem constants: B=16, C=5, H=512, W=512
constexpr int Bn      = 16;
constexpr int Cn      = 5;
constexpr int HW      = 512 * 512;        // 262144
constexpr int HW4     = HW / 4;           // 65536 float4 groups per (b,c) plane
constexpr int NVEC    = Bn * HW / 4;      // 1,048,576 4-pixel groups
constexpr int NBLK    = 1024;             // one residency round (4 blk/CU x 256 CU)
constexpr int THREADS = 256;
constexpr int STRIDE  = NBLK * THREADS;   // 262144 == NVEC/4; +STRIDE => batch+4, same hw4
constexpr float SCALE = 1.0f / (float)(Bn * HW);

__device__ __forceinline__ float block_reduce_256(float v) {
    #pragma unroll
    for (int off = 32; off > 0; off >>= 1)
        v += __shfl_down(v, off, 64);
    __shared__ float s[4];
    const int lane = threadIdx.x & 63;
    const int wid  = threadIdx.x >> 6;
    if (lane == 0) s[wid] = v;
    __syncthreads();
    if (threadIdx.x == 0) v = (s[0] + s[1]) + (s[2] + s[3]);
    return v;
}

__device__ __forceinline__ float pixel_pen(float l0, float l1, float l2, float l3,
                                           float l4, int t) {
    // relu terms on unnormalized exps; single divide by partition sum (S>0).
    float m  = fmaxf(fmaxf(fmaxf(l0, l1), fmaxf(l2, l3)), l4);
    float e0 = __expf(l0 - m);
    float e1 = __expf(l1 - m);
    float e2 = __expf(l2 - m);
    float e3 = __expf(l3 - m);
    float e4 = __expf(l4 - m);
    float S  = ((e0 + e1) + (e2 + e3)) + e4;
    float d1 = e1 - e0;
    float d2 = e2 - e1;
    float d3 = e3 - e2;
    float d4 = e4 - e3;
    float pen = 0.0f;
    pen += (t >= 1) ? fmaxf(-d1, 0.0f) : fmaxf(d1, 0.0f);
    pen += (t >= 2) ? fmaxf(-d2, 0.0f) : fmaxf(d2, 0.0f);
    pen += (t >= 3) ? fmaxf(-d3, 0.0f) : fmaxf(d3, 0.0f);
    pen += (t >= 4) ? fmaxf(-d4, 0.0f) : fmaxf(d4, 0.0f);
    return pen / S;
}

struct Grp { float4 x0, x1, x2, x3, x4; int4 t; };

__device__ __forceinline__ Grp load_grp(const float4* __restrict__ p,
                                        const int4* __restrict__ lab, int v) {
    Grp g;
    g.t  = lab[v];
    g.x0 = p[0 * HW4];
    g.x1 = p[1 * HW4];
    g.x2 = p[2 * HW4];
    g.x3 = p[3 * HW4];
    g.x4 = p[4 * HW4];
    return g;
}

__device__ __forceinline__ float group_pen(const Grp& g) {
    float a = 0.0f;
    a += pixel_pen(g.x0.x, g.x1.x, g.x2.x, g.x3.x, g.x4.x, g.t.x);
    a += pixel_pen(g.x0.y, g.x1.y, g.x2.y, g.x3.y, g.x4.y, g.t.y);
    a += pixel_pen(g.x0.z, g.x1.z, g.x2.z, g.x3.z, g.x4.z, g.t.z);
    a += pixel_pen(g.x0.w, g.x1.w, g.x2.w, g.x3.w, g.x4.w, g.t.w);
    return a;
}

// 4 waves/SIMD -> <=128 VGPRs; double-buffered: load g[k+1] while computing g[k].
__global__ void __launch_bounds__(256, 4)
o2_loss_partial(const float4* __restrict__ pred,   // (B, 5, H, W) as float4
                const int4*  __restrict__ lab,     // (B, H, W) as int4
                float* __restrict__ partial) {
    const int tid = threadIdx.x;
    const int v0  = blockIdx.x * THREADS + tid;    // in [0, STRIDE)
    const int b0  = v0 >> 16;                      // in [0, 4)
    const int h0  = v0 & (HW4 - 1);
    const float4* p = pred + (size_t)b0 * (Cn * HW4) + h0;
    constexpr int PB = 4 * (Cn * HW4);             // batch+4 step in float4s

    Grp ga = load_grp(p, lab, v0);                                 // g0
    Grp gb = load_grp(p + PB, lab, v0 + STRIDE);                   // g1
    float acc = group_pen(ga);                                     // compute g0
    ga = load_grp(p + 2 * PB, lab, v0 + 2 * STRIDE);               // g2
    acc += group_pen(gb);                                          // compute g1
    gb = load_grp(p + 3 * PB, lab, v0 + 3 * STRIDE);               // g3
    acc += group_pen(ga);                                          // compute g2
    acc += group_pen(gb);                                          // compute g3

    float bsum = block_reduce_256(acc);
    if (tid == 0) partial[blockIdx.x] = bsum;      // plain store, no atomics
}

// Single-wave finalize: no LDS, no __syncthreads, 4 independent float4 loads
// per lane (one memory round trip), shuffle reduce, one store.
__global__ void __launch_bounds__(64)
o2_loss_finalize(const float4* __restrict__ partial4, float* __restrict__ out) {
    const int lane = threadIdx.x;                  // 0..63
    float4 x0 = partial4[lane];
    float4 x1 = partial4[lane + 64];
    float4 x2 = partial4[lane + 128];
    float4 x3 = partial4[lane + 192];
    float v = (((x0.x + x0.y) + (x0.z + x0.w)) + ((x1.x + x1.y) + (x1.z + x1.w)))
            + (((x2.x + x2.y) + (x2.z + x2.w)) + ((x3.x + x3.y) + (x3.z + x3.w)));
    #pragma unroll
    for (int off = 32; off > 0; off >>= 1)
        v += __shfl_down(v, off, 64);
    if (lane == 0) out[0] = v * SCALE;
}

extern "C" void kernel_launch(void* const* d_in, const int* in_sizes, int n_in,
                              void* d_out, int out_size, void* d_ws, size_t ws_size,
                              hipStream_t stream) {
    const float4* pred = (const float4*)d_in[0];
    const int4*   lab  = (const int4*)d_in[1];
    float* partial = (float*)d_ws;          // 1024 floats = 4 KB scratch
    float* out     = (float*)d_out;

    o2_loss_partial<<<NBLK, THREADS, 0, stream>>>(pred, lab, partial);
    o2_loss_finalize<<<1, 64, 0, stream>>>((const float4*)partial, out);
}